// Round 5
// baseline (6521.345 us; speedup 1.0000x reference)
//
#include <hip/hip_runtime.h>
#include <hip/hip_bf16.h>
#include <math.h>

#define B 256
#define S 100
#define H 512
#define E 512
#define R 50
#define NC 5

__device__ __forceinline__ float selu_f(float x){
    return x > 0.0f ? 1.0507009873554805f * x
                    : 1.7580993408473766f * expm1f(x);   // scale*alpha
}

__device__ __forceinline__ float wred_maxf(float v){
    #pragma unroll
    for (int o = 32; o > 0; o >>= 1) v = fmaxf(v, __shfl_xor(v, o));
    return v;
}
__device__ __forceinline__ double wred_sum_d(double v){
    #pragma unroll
    for (int o = 32; o > 0; o >>= 1) v += __shfl_xor(v, o);
    return v;
}

// ---------------- attention (literal, per step, includes h-term) ----------------
__global__ __launch_bounds__(256) void k_attn(
    const float* __restrict__ h, const float* __restrict__ enc,
    const float* __restrict__ W_attn, const float* __restrict__ b_attn,
    float* __restrict__ ctx)
{
    __shared__ float sco[128];
    __shared__ double red[128];
    __shared__ double hdot_sh;
    const int b = blockIdx.x, t = threadIdx.x;
    const int wv = t >> 6, ln = t & 63;
    if (wv == 0){
        double a = 0.0;
        #pragma unroll
        for (int u = 0; u < 8; ++u)
            a = fma((double)h[(size_t)b*H + ln + 64*u], (double)W_attn[ln + 64*u], a);
        a = wred_sum_d(a);
        if (ln == 0) hdot_sh = a;
    }
    __syncthreads();
    const double hdot = hdot_sh + (double)b_attn[0];
    const float* eb = enc + (size_t)b * S * H;
    for (int s = wv; s < S; s += 4){
        const float* es = eb + (size_t)s * H;
        double a = 0.0;
        #pragma unroll
        for (int u = 0; u < 8; ++u)
            a = fma((double)es[ln + 64*u], (double)W_attn[H + ln + 64*u], a);
        a = wred_sum_d(a);
        if (ln == 0) sco[s] = (float)(hdot + a);       // f32 score (as reference materializes)
    }
    __syncthreads();
    float vm = (t < S) ? sco[t] : -INFINITY;
    if (t < 128) red[t] = (double)vm;
    __syncthreads();
    for (int st = 64; st > 0; st >>= 1){ if (t < st) red[t] = fmax(red[t], red[t+st]); __syncthreads(); }
    const float m = (float)red[0];
    __syncthreads();
    float e = (t < S) ? expf(sco[t] - m) : 0.f;        // f32 exp
    if (t < 128) red[t] = (double)e;
    __syncthreads();
    for (int st = 64; st > 0; st >>= 1){ if (t < st) red[t] += red[t+st]; __syncthreads(); }
    const float fsum = (float)red[0];
    __syncthreads();
    if (t < S) sco[t] = e / fsum;                      // f32 aw
    __syncthreads();
    for (int hh = t; hh < H; hh += 256){
        double a = 0.0;
        for (int s = 0; s < S; ++s)
            a = fma((double)sco[s], (double)eb[(size_t)s*H + hh], a);
        ctx[(size_t)b*H + hh] = (float)a;
    }
}

// ---------------- xin = [emb | ctx] ----------------
__global__ __launch_bounds__(256) void k_concat(
    const float* __restrict__ emb, const float* __restrict__ ctx,
    float* __restrict__ xin)
{
    const int idx = blockIdx.x * 256 + threadIdx.x;    // B*1024
    const int b = idx >> 10, k = idx & 1023;
    xin[idx] = (k < H) ? emb[(size_t)b*E + k] : ctx[(size_t)b*H + (k - H)];
}

// ---------------- tiled GEMM (f32 in, f64 acc, f32 out): C = A @ W^T + bias ----------------
__device__ __forceinline__ void gemm_body(
    const float* __restrict__ A, int lda,
    const float* __restrict__ W, int ldw,
    const float* __restrict__ bias,
    float* __restrict__ C, int ldc,
    int N, int K, int m0, int n0)
{
    __shared__ float As[16][65];
    __shared__ float Ws[16][65];
    const int t = threadIdx.x;
    const int tx = t & 15, ty = t >> 4;
    const int lm = t >> 2, lk = (t & 3) << 2;
    double acc[4][4] = {};
    for (int k0 = 0; k0 < K; k0 += 16){
        float4 a = *(const float4*)(A + (size_t)(m0 + lm) * lda + k0 + lk);
        As[lk  ][lm] = a.x; As[lk+1][lm] = a.y; As[lk+2][lm] = a.z; As[lk+3][lm] = a.w;
        float4 w = make_float4(0.f, 0.f, 0.f, 0.f);
        int n = n0 + lm;
        if (n < N) w = *(const float4*)(W + (size_t)n * ldw + k0 + lk);
        Ws[lk  ][lm] = w.x; Ws[lk+1][lm] = w.y; Ws[lk+2][lm] = w.z; Ws[lk+3][lm] = w.w;
        __syncthreads();
        #pragma unroll
        for (int kk = 0; kk < 16; ++kk){
            double a0 = As[kk][ty*4+0], a1 = As[kk][ty*4+1], a2 = As[kk][ty*4+2], a3 = As[kk][ty*4+3];
            double b0 = Ws[kk][tx*4+0], b1 = Ws[kk][tx*4+1], b2 = Ws[kk][tx*4+2], b3 = Ws[kk][tx*4+3];
            acc[0][0] = fma(a0,b0,acc[0][0]); acc[0][1] = fma(a0,b1,acc[0][1]);
            acc[0][2] = fma(a0,b2,acc[0][2]); acc[0][3] = fma(a0,b3,acc[0][3]);
            acc[1][0] = fma(a1,b0,acc[1][0]); acc[1][1] = fma(a1,b1,acc[1][1]);
            acc[1][2] = fma(a1,b2,acc[1][2]); acc[1][3] = fma(a1,b3,acc[1][3]);
            acc[2][0] = fma(a2,b0,acc[2][0]); acc[2][1] = fma(a2,b1,acc[2][1]);
            acc[2][2] = fma(a2,b2,acc[2][2]); acc[2][3] = fma(a2,b3,acc[2][3]);
            acc[3][0] = fma(a3,b0,acc[3][0]); acc[3][1] = fma(a3,b1,acc[3][1]);
            acc[3][2] = fma(a3,b2,acc[3][2]); acc[3][3] = fma(a3,b3,acc[3][3]);
        }
        __syncthreads();
    }
    #pragma unroll
    for (int i = 0; i < 4; ++i){
        int m = m0 + ty*4 + i;
        #pragma unroll
        for (int j = 0; j < 4; ++j){
            int n = n0 + tx*4 + j;
            if (n < N){
                double vv = acc[i][j];
                if (bias) vv += (double)bias[n];
                C[(size_t)m * ldc + n] = (float)vv;
            }
        }
    }
}

__global__ __launch_bounds__(256) void k_gemm(
    const float* A, int lda, const float* W, int ldw,
    const float* bias, float* C, int ldc, int N, int K)
{
    gemm_body(A, lda, W, ldw, bias, C, ldc, N, K, blockIdx.y * 64, blockIdx.x * 64);
}

// ---------------- GRU combine (literal f32 elementwise) ----------------
__global__ __launch_bounds__(256) void k_combine(
    const float* __restrict__ gi, const float* __restrict__ gh,
    const float* __restrict__ hold, float* __restrict__ hnew,
    float* __restrict__ sh)
{
    const int idx = blockIdx.x * 256 + threadIdx.x;    // B*H
    const int b = idx >> 9, g = idx & (H - 1);
    const size_t base = (size_t)b * 3 * H;
    const float ir = gi[base + g],         hr = gh[base + g];
    const float iz = gi[base + H + g],     hz = gh[base + H + g];
    const float in_ = gi[base + 2*H + g],  hn = gh[base + 2*H + g];
    const float r = 1.f / (1.f + expf(-(ir + hr)));
    const float z = 1.f / (1.f + expf(-(iz + hz)));
    const float n = tanhf(in_ + r * hn);
    const float h = hold[idx];
    const float hv = (1.f - z) * n + z * h;
    hnew[idx] = hv;
    sh[idx] = selu_f(hv);
}

__global__ __launch_bounds__(256) void k_hinit(
    const float* __restrict__ dec, const float* __restrict__ prev,
    float* __restrict__ h)
{
    const int idx = blockIdx.x * 256 + threadIdx.x;
    h[idx] = 0.5f * (dec[idx] + (prev ? prev[idx] : 0.f));
}

__global__ __launch_bounds__(256) void k_emb_init(
    const float* __restrict__ sos, float* __restrict__ emb)
{
    const int idx = blockIdx.x * 256 + threadIdx.x;
    emb[idx] = sos[idx & (E - 1)];
}

// ---------------- pred logits (50 rel + eos), f64 dot -> f32 ----------------
__global__ __launch_bounds__(256) void k_pred51(
    const float* __restrict__ h, const float* __restrict__ Wp,
    const float* __restrict__ bp, const float* __restrict__ We,
    const float* __restrict__ be, float* __restrict__ plog)
{
    const int w = (blockIdx.x << 2) + (threadIdx.x >> 6);
    const int ln = threadIdx.x & 63;
    if (w >= B * (R + 1)) return;
    const int b = w / (R + 1), i = w % (R + 1);
    const float* hr = h + (size_t)b * H;
    const float* wr = (i < R) ? Wp + (size_t)i * H : We;
    double a = 0.0;
    #pragma unroll
    for (int u = 0; u < H/64; ++u) a = fma((double)hr[ln + 64*u], (double)wr[ln + 64*u], a);
    a = wred_sum_d(a);
    if (ln == 0) plog[w] = (float)(a + (double)(i < R ? bp[i] : be[0]));
}

__global__ __launch_bounds__(256) void k_eos(
    const float* __restrict__ h, const float* __restrict__ We,
    const float* __restrict__ be, float* __restrict__ eosb)
{
    const int w = (blockIdx.x << 2) + (threadIdx.x >> 6);
    const int ln = threadIdx.x & 63;
    if (w >= B) return;
    const float* hr = h + (size_t)w * H;
    double a = 0.0;
    #pragma unroll
    for (int u = 0; u < H/64; ++u) a = fma((double)hr[ln + 64*u], (double)We[ln + 64*u], a);
    a = wred_sum_d(a);
    if (ln == 0) eosb[w] = (float)(a + (double)be[0]);
}

// ---------------- rel finish: f32 log_softmax(51), argmax on q, gather ----------------
__global__ __launch_bounds__(64) void k_rel_finish(
    const float* __restrict__ plog, const float* __restrict__ rel_emb,
    float* __restrict__ out_rel, int c,
    float* __restrict__ emb, float* __restrict__ out_act)
{
    const int b = blockIdx.x, ln = threadIdx.x;
    const float v = (ln < R + 1) ? plog[b * (R + 1) + ln] : -INFINITY;
    const float m = wred_maxf(v);
    const float p = v - m;                               // f32 (ref materializes)
    const float e = (ln < R + 1) ? expf(p) : 0.f;
    const double sum = wred_sum_d((double)e);
    const float lse = logf((float)sum);
    const float q = p - lse;                             // f32 log_softmax value
    // argmax on q (reference argmaxes the log_softmax output), first index on ties
    float bv = q; int bi = ln;
    #pragma unroll
    for (int o = 32; o > 0; o >>= 1){
        float ov = __shfl_xor(bv, o);
        int   oi = __shfl_xor(bi, o);
        if (ov > bv || (ov == bv && oi < bi)){ bv = ov; bi = oi; }
    }
    if (ln < R + 1)
        out_rel[(size_t)c * B * (R+1) + (size_t)b * (R+1) + ln] = q;
    const int act = bi;
    if (ln == 0) out_act[(size_t)(3*c) * B + b] = (float)act;
    const float* er = rel_emb + (size_t)act * E;
    float* ebp = emb + (size_t)b * E;
    #pragma unroll
    for (int u = 0; u < E/64; ++u) ebp[ln + 64*u] = er[ln + 64*u];
}

// ---------------- fused copy-score GEMM (literal: one K=1024 virtual-concat dot) ----------------
// crow[m] = f32( sum_n selu_f32(f32(dot_1024) + bf[n]) * wc[n] + bcopy ),  m = b*100+s
__global__ __launch_bounds__(256) void k_fused(
    const float* __restrict__ sh, const float* __restrict__ enc,
    const float* __restrict__ W_fuse, const float* __restrict__ b_fuse,
    const float* __restrict__ W_copy, const float* __restrict__ b_copy,
    float* __restrict__ crow)
{
    __shared__ float As[16][65];
    __shared__ float Ws[16][129];
    const int t = threadIdx.x;
    const int m0 = blockIdx.x * 64;
    const int tx = t & 15, ty = t >> 4;        // tx: 8-col group, ty: 4-row group
    const int lm = t >> 2, lk = (t & 3) << 2;  // A loader
    const int lw = t >> 1, lkw = (t & 1) << 3; // W loader
    const int am = m0 + lm;
    const int ab = am / 100;
    double acc[4][8] = {};
    for (int k0 = 0; k0 < 2*H; k0 += 16){
        float4 a;
        if (k0 < H){
            a = *(const float4*)(sh + (size_t)ab * H + k0 + lk);
        } else {
            a = *(const float4*)(enc + (size_t)am * H + (k0 + lk - H));
            a.x = selu_f(a.x); a.y = selu_f(a.y); a.z = selu_f(a.z); a.w = selu_f(a.w);
        }
        As[lk  ][lm] = a.x; As[lk+1][lm] = a.y; As[lk+2][lm] = a.z; As[lk+3][lm] = a.w;
        if (lw < 100){
            const float* wrow = W_fuse + (size_t)lw * (2*H) + k0 + lkw;
            float4 w0 = *(const float4*)(wrow);
            float4 w1 = *(const float4*)(wrow + 4);
            Ws[lkw  ][lw] = w0.x; Ws[lkw+1][lw] = w0.y; Ws[lkw+2][lw] = w0.z; Ws[lkw+3][lw] = w0.w;
            Ws[lkw+4][lw] = w1.x; Ws[lkw+5][lw] = w1.y; Ws[lkw+6][lw] = w1.z; Ws[lkw+7][lw] = w1.w;
        } else {
            #pragma unroll
            for (int q = 0; q < 8; ++q) Ws[lkw+q][lw] = 0.f;
        }
        __syncthreads();
        #pragma unroll
        for (int kk = 0; kk < 16; ++kk){
            double av[4], wv[8];
            #pragma unroll
            for (int i = 0; i < 4; ++i) av[i] = (double)As[kk][ty*4+i];
            #pragma unroll
            for (int j = 0; j < 8; ++j) wv[j] = (double)Ws[kk][tx*8+j];
            #pragma unroll
            for (int i = 0; i < 4; ++i)
                #pragma unroll
                for (int j = 0; j < 8; ++j)
                    acc[i][j] = fma(av[i], wv[j], acc[i][j]);
        }
        __syncthreads();
    }
    const double bc = (double)b_copy[0];
    #pragma unroll
    for (int i = 0; i < 4; ++i){
        double part = 0.0;
        #pragma unroll
        for (int j = 0; j < 8; ++j){
            int n = tx*8 + j;
            if (n < 100){
                float f2 = selu_f((float)(acc[i][j] + (double)b_fuse[n]));  // f32 fused2
                part += (double)f2 * (double)W_copy[n];
            }
        }
        #pragma unroll
        for (int o = 1; o < 16; o <<= 1) part += __shfl_xor(part, o);
        if (tx == 0) crow[m0 + ty*4 + i] = (float)(part + bc);
    }
}

// ---------------- copy finish: f32 log_softmax(101), argmax on q, gather ----------------
__global__ __launch_bounds__(64) void k_copy_finish(
    const float* __restrict__ crow, const float* __restrict__ eosb,
    const int* __restrict__ sentence, const float* __restrict__ word_emb,
    float* __restrict__ out_copy, int slot,
    float* __restrict__ emb, float* __restrict__ out_act, int aslot)
{
    const int b = blockIdx.x, ln = threadIdx.x;
    const float* cb = crow + (size_t)b * S;
    const float v1 = cb[ln];
    const int i2 = ln + 64;
    const float v2 = (i2 < S) ? cb[i2] : (i2 == S ? eosb[b] : -INFINITY);
    const float m = wred_maxf(fmaxf(v1, v2));
    const float p1 = v1 - m;
    const float p2 = v2 - m;
    double e = (double)expf(p1) + ((i2 <= S) ? (double)expf(p2) : 0.0);
    const double sum = wred_sum_d(e);
    const float lse = logf((float)sum);
    const float q1 = p1 - lse;
    const float q2 = p2 - lse;
    float bv; int bi;
    if (q2 > q1){ bv = q2; bi = i2; } else { bv = q1; bi = ln; }
    #pragma unroll
    for (int o = 32; o > 0; o >>= 1){
        float ov = __shfl_xor(bv, o);
        int   oi = __shfl_xor(bi, o);
        if (ov > bv || (ov == bv && oi < bi)){ bv = ov; bi = oi; }
    }
    const size_t obase = (size_t)slot * B * (S+1) + (size_t)b * (S+1);
    out_copy[obase + ln] = q1;
    if (i2 <= S) out_copy[obase + i2] = q2;
    const int act = bi;
    if (ln == 0) out_act[(size_t)aslot * B + b] = (float)act;
    const int wd = sentence[b * S + (act < S ? act : S - 1)];
    const float* wr = word_emb + (size_t)wd * E;
    float* ebp = emb + (size_t)b * E;
    #pragma unroll
    for (int u = 0; u < E/64; ++u) ebp[ln + 64*u] = wr[ln + 64*u];
}

extern "C" void kernel_launch(void* const* d_in, const int* in_sizes, int n_in,
                              void* d_out, int out_size, void* d_ws, size_t ws_size,
                              hipStream_t stream)
{
    (void)in_sizes; (void)n_in; (void)out_size; (void)ws_size;
    const int*   sentence = (const int*)  d_in[0];
    const float* dec      = (const float*)d_in[1];
    const float* enc      = (const float*)d_in[2];
    const float* word_emb = (const float*)d_in[3];
    const float* rel_emb  = (const float*)d_in[4];
    const float* sos      = (const float*)d_in[5];
    const float* W_comb   = (const float*)d_in[6];
    const float* b_comb   = (const float*)d_in[7];
    const float* W_attn   = (const float*)d_in[8];
    const float* b_attn   = (const float*)d_in[9];
    const float* W_ih     = (const float*)d_in[10];
    const float* W_hh     = (const float*)d_in[11];
    const float* b_ih     = (const float*)d_in[12];
    const float* b_hh     = (const float*)d_in[13];
    const float* W_eos    = (const float*)d_in[14];
    const float* b_eos    = (const float*)d_in[15];
    const float* W_pred   = (const float*)d_in[16];
    const float* b_pred   = (const float*)d_in[17];
    const float* W_fuse   = (const float*)d_in[18];
    const float* b_fuse   = (const float*)d_in[19];
    const float* W_copy   = (const float*)d_in[20];
    const float* b_copy   = (const float*)d_in[21];

    // OUTPUT IS FLOAT32 (reference returns f32/f32/int32; "else float*" per spec).
    float* out       = (float*)d_out;
    float* out_rel   = out;
    float* out_copy  = out + (size_t)NC * B * (R + 1);
    float* out_act   = out_copy + (size_t)2 * NC * B * (S + 1);

    float* p = (float*)d_ws;
    float* emb  = p; p += B * E;
    float* ctx  = p; p += B * H;
    float* xin  = p; p += B * (H + E);
    float* xb   = p; p += B * E;
    float* gi   = p; p += B * 3 * H;
    float* gh   = p; p += B * 3 * H;
    float* hb0  = p; p += B * H;
    float* hb1  = p; p += B * H;
    float* sh   = p; p += B * H;
    float* plog = p; p += B * (R + 1);
    float* crow = p; p += B * S;
    float* eosb = p; p += B;
    float* hb[2] = { hb0, hb1 };

    k_emb_init<<<(B*E)/256, 256, 0, stream>>>(sos, emb);

    int cur = 0;
    for (int c = 0; c < NC; ++c){
        if (c == 0){
            k_hinit<<<(B*H)/256, 256, 0, stream>>>(dec, nullptr, hb[0]);
            cur = 0;
        } else {
            k_hinit<<<(B*H)/256, 256, 0, stream>>>(dec, hb[cur], hb[cur^1]);
            cur ^= 1;
        }
        for (int t3 = 0; t3 < 3; ++t3){
            // attention (literal, includes h-term)
            k_attn<<<B, 256, 0, stream>>>(hb[cur], enc, W_attn, b_attn, ctx);
            // x = [emb | ctx] @ W_comb^T + b_comb   (single K=1024 dot, literal)
            k_concat<<<(B*(H+E))/256, 256, 0, stream>>>(emb, ctx, xin);
            k_gemm<<<dim3(E/64, B/64), 256, 0, stream>>>(xin, H+E, W_comb, H+E,
                                                         b_comb, xb, E, E, H+E);
            // GRU
            k_gemm<<<dim3(3*H/64, B/64), 256, 0, stream>>>(
                xb, E, W_ih + (size_t)c * 3 * H * E, E,
                b_ih + (size_t)c * 3 * H, gi, 3*H, 3*H, E);
            k_gemm<<<dim3(3*H/64, B/64), 256, 0, stream>>>(
                hb[cur], H, W_hh + (size_t)c * 3 * H * H, H,
                b_hh + (size_t)c * 3 * H, gh, 3*H, 3*H, H);
            k_combine<<<(B*H)/256, 256, 0, stream>>>(gi, gh, hb[cur], hb[cur^1], sh);
            cur ^= 1;
            if (t3 == 0){
                k_pred51<<<(B*(R+1))/4, 256, 0, stream>>>(hb[cur], W_pred, b_pred,
                                                          W_eos, b_eos, plog);
                k_rel_finish<<<B, 64, 0, stream>>>(plog, rel_emb, out_rel, c, emb, out_act);
            } else {
                k_eos<<<B/4, 256, 0, stream>>>(hb[cur], W_eos, b_eos, eosb);
                k_fused<<<(B*S)/64, 256, 0, stream>>>(sh, enc, W_fuse, b_fuse,
                                                      W_copy, b_copy, crow);
                k_copy_finish<<<B, 64, 0, stream>>>(crow, eosb, sentence, word_emb,
                                                    out_copy, 2*c + (t3-1),
                                                    emb, out_act, 3*c + t3);
            }
        }
    }
}

// Round 6
// 2070.603 us; speedup vs baseline: 3.1495x; 3.1495x over previous
//
#include <hip/hip_runtime.h>
#include <hip/hip_bf16.h>
#include <math.h>

#define B 256
#define S 100
#define H 512
#define E 512
#define R 50
#define NC 5

__device__ __forceinline__ float selu_f(float x){
    return x > 0.0f ? 1.0507009873554805f * x
                    : 1.7580993408473766f * expm1f(x);   // scale*alpha
}

__device__ __forceinline__ float wred_sum(float v){
    #pragma unroll
    for (int o = 32; o > 0; o >>= 1) v += __shfl_xor(v, o);
    return v;
}
__device__ __forceinline__ float wred_maxf(float v){
    #pragma unroll
    for (int o = 32; o > 0; o >>= 1) v = fmaxf(v, __shfl_xor(v, o));
    return v;
}

// ---------------- attention context (loop-invariant: h-term cancels in softmax) ----------------
__global__ __launch_bounds__(256) void k_ctx(const float* __restrict__ enc,
                                             const float* __restrict__ W_attn,
                                             float* __restrict__ ctx)
{
    __shared__ float sc[128];
    __shared__ float red[128];
    const int b = blockIdx.x;
    const int t = threadIdx.x;
    const int wv = t >> 6, ln = t & 63;
    const float* eb = enc + (size_t)b * S * H;
    const float* wa = W_attn + H;          // enc-part of W_attn
    for (int s = wv; s < S; s += 4){
        const float* es = eb + (size_t)s * H;
        float a = 0.f;
        #pragma unroll
        for (int u = 0; u < H/64; ++u) a += es[ln + 64*u] * wa[ln + 64*u];
        a = wred_sum(a);
        if (ln == 0) sc[s] = a;
    }
    __syncthreads();
    float vm = (t < S) ? sc[t] : -INFINITY;
    if (t < 128) red[t] = vm;
    __syncthreads();
    for (int st = 64; st > 0; st >>= 1){
        if (t < st) red[t] = fmaxf(red[t], red[t + st]);
        __syncthreads();
    }
    const float m = red[0];
    __syncthreads();
    float e = (t < S) ? expf(sc[t] - m) : 0.f;
    if (t < 128) red[t] = e;
    __syncthreads();
    for (int st = 64; st > 0; st >>= 1){
        if (t < st) red[t] += red[t + st];
        __syncthreads();
    }
    const float sum = red[0];
    __syncthreads();
    if (t < S) sc[t] = e / sum;
    __syncthreads();
    for (int hh = t; hh < H; hh += 256){
        float a = 0.f;
        for (int s = 0; s < S; ++s) a += sc[s] * eb[(size_t)s * H + hh];
        ctx[(size_t)b * H + hh] = a;
    }
}

// ---------------- tiled f32 GEMM: C[M,N] = (seluA?)A[M,K] @ W[N,:K]^T + bias + addm ----------------
__device__ __forceinline__ void gemm_body(
    const float* __restrict__ A, int lda,
    const float* __restrict__ W, int ldw,
    const float* __restrict__ bias,
    const float* __restrict__ addm,
    float* __restrict__ C, int ldc,
    int N, int K, int m0, int n0, int seluA)
{
    __shared__ float As[16][65];
    __shared__ float Ws[16][65];
    const int t = threadIdx.x;
    const int tx = t & 15, ty = t >> 4;
    const int lm = t >> 2, lk = (t & 3) << 2;
    float acc[4][4] = {};
    for (int k0 = 0; k0 < K; k0 += 16){
        float4 a = *(const float4*)(A + (size_t)(m0 + lm) * lda + k0 + lk);
        if (seluA){ a.x = selu_f(a.x); a.y = selu_f(a.y); a.z = selu_f(a.z); a.w = selu_f(a.w); }
        As[lk  ][lm] = a.x; As[lk+1][lm] = a.y; As[lk+2][lm] = a.z; As[lk+3][lm] = a.w;
        float4 w = make_float4(0.f, 0.f, 0.f, 0.f);
        int n = n0 + lm;
        if (n < N) w = *(const float4*)(W + (size_t)n * ldw + k0 + lk);
        Ws[lk  ][lm] = w.x; Ws[lk+1][lm] = w.y; Ws[lk+2][lm] = w.z; Ws[lk+3][lm] = w.w;
        __syncthreads();
        #pragma unroll
        for (int kk = 0; kk < 16; ++kk){
            float a0 = As[kk][ty*4+0], a1 = As[kk][ty*4+1], a2 = As[kk][ty*4+2], a3 = As[kk][ty*4+3];
            float b0 = Ws[kk][tx*4+0], b1 = Ws[kk][tx*4+1], b2 = Ws[kk][tx*4+2], b3 = Ws[kk][tx*4+3];
            acc[0][0] += a0*b0; acc[0][1] += a0*b1; acc[0][2] += a0*b2; acc[0][3] += a0*b3;
            acc[1][0] += a1*b0; acc[1][1] += a1*b1; acc[1][2] += a1*b2; acc[1][3] += a1*b3;
            acc[2][0] += a2*b0; acc[2][1] += a2*b1; acc[2][2] += a2*b2; acc[2][3] += a2*b3;
            acc[3][0] += a3*b0; acc[3][1] += a3*b1; acc[3][2] += a3*b2; acc[3][3] += a3*b3;
        }
        __syncthreads();
    }
    #pragma unroll
    for (int i = 0; i < 4; ++i){
        int m = m0 + ty*4 + i;
        #pragma unroll
        for (int j = 0; j < 4; ++j){
            int n = n0 + tx*4 + j;
            if (n < N){
                float vv = acc[i][j];
                if (bias) vv += bias[n];
                if (addm) vv += addm[(size_t)m * ldc + n];
                C[(size_t)m * ldc + n] = vv;
            }
        }
    }
}

__global__ __launch_bounds__(256) void k_gemm(
    const float* A, int lda, const float* W, int ldw,
    const float* bias, const float* addm, float* C, int ldc,
    int N, int K, int seluA)
{
    gemm_body(A, lda, W, ldw, bias, addm, C, ldc, N, K,
              blockIdx.y * 64, blockIdx.x * 64, seluA);
}

// gi = x @ Wih^T + bih ; gh = h @ Whh^T + bhh  (one launch, N=3072 virtual)
__global__ __launch_bounds__(256) void k_gru_gemm(
    const float* x, const float* h,
    const float* Wih, const float* Whh,
    const float* bih, const float* bhh,
    float* gi, float* gh)
{
    int n0 = blockIdx.x * 64;
    const float* A; const float* W; const float* bias; float* C;
    if (n0 < 3*H){ A = x; W = Wih; bias = bih; C = gi; }
    else         { A = h; W = Whh; bias = bhh; C = gh; n0 -= 3*H; }
    gemm_body(A, H, W, H, bias, nullptr, C, 3*H, 3*H, H, blockIdx.y * 64, n0, 0);
}

// ---------------- GRU gate combine ----------------
__global__ __launch_bounds__(256) void k_combine(
    const float* __restrict__ gi, const float* __restrict__ gh,
    const float* __restrict__ hold, float* __restrict__ hnew,
    float* __restrict__ sh)
{
    const int idx = blockIdx.x * 256 + threadIdx.x;      // B*H
    const int b = idx >> 9, g = idx & (H - 1);
    const size_t base = (size_t)b * 3 * H;
    const float ir = gi[base + g],         hr = gh[base + g];
    const float iz = gi[base + H + g],     hz = gh[base + H + g];
    const float in_ = gi[base + 2*H + g],  hn = gh[base + 2*H + g];
    const float r = 1.f / (1.f + expf(-(ir + hr)));
    const float z = 1.f / (1.f + expf(-(iz + hz)));
    const float n = tanhf(in_ + r * hn);
    const float h = hold[idx];
    const float hv = (1.f - z) * n + z * h;
    hnew[idx] = hv;
    sh[idx] = selu_f(hv);
}

__global__ __launch_bounds__(256) void k_hinit(
    const float* __restrict__ dec, const float* __restrict__ prev,
    float* __restrict__ h)
{
    const int idx = blockIdx.x * 256 + threadIdx.x;
    h[idx] = 0.5f * (dec[idx] + (prev ? prev[idx] : 0.f));
}

__global__ __launch_bounds__(256) void k_emb_init(
    const float* __restrict__ sos, float* __restrict__ emb)
{
    const int idx = blockIdx.x * 256 + threadIdx.x;
    emb[idx] = sos[idx & (E - 1)];
}

// ---------------- fused rel step: 51 logits + log_softmax + argmax + gather (block per b) ----------------
__global__ __launch_bounds__(256) void k_rel_step(
    const float* __restrict__ h,
    const float* __restrict__ Wp, const float* __restrict__ bp,
    const float* __restrict__ We, const float* __restrict__ be,
    const float* __restrict__ rel_emb,
    float* __restrict__ out_rel, int c,
    float* __restrict__ emb, float* __restrict__ out_act)
{
    __shared__ float logits[R + 1];
    __shared__ int   act_sh;
    const int b = blockIdx.x, t = threadIdx.x;
    const int wv = t >> 6, ln = t & 63;
    const float* hr = h + (size_t)b * H;
    for (int i = wv; i < R + 1; i += 4){
        const float* wr = (i < R) ? Wp + (size_t)i * H : We;
        float a = 0.f;
        #pragma unroll
        for (int u = 0; u < H/64; ++u) a += hr[ln + 64*u] * wr[ln + 64*u];
        a = wred_sum(a);
        if (ln == 0) logits[i] = a + (i < R ? bp[i] : be[0]);
    }
    __syncthreads();
    if (wv == 0){
        const float v = (ln < R + 1) ? logits[ln] : -INFINITY;
        const float m = wred_maxf(v);
        const float p = v - m;
        const float e = (ln < R + 1) ? expf(p) : 0.f;
        const float lse = logf(wred_sum(e));
        const float q = p - lse;
        float bv = q; int bi = ln;
        #pragma unroll
        for (int o = 32; o > 0; o >>= 1){
            float ov = __shfl_xor(bv, o);
            int   oi = __shfl_xor(bi, o);
            if (ov > bv || (ov == bv && oi < bi)){ bv = ov; bi = oi; }
        }
        if (ln < R + 1)
            out_rel[(size_t)c * B * (R+1) + (size_t)b * (R+1) + ln] = q;
        if (ln == 0){
            out_act[(size_t)(3*c) * B + b] = (float)bi;
            act_sh = bi;
        }
    }
    __syncthreads();
    const float* er = rel_emb + (size_t)act_sh * E;
    float* ebp = emb + (size_t)b * E;
    #pragma unroll
    for (int u = 0; u < 2; ++u) ebp[t + 256*u] = er[t + 256*u];
}

// ---------------- fused copy step: eos + u + 100 scores + log_softmax(101) + argmax + gather ----------------
__global__ __launch_bounds__(256) void k_copy_step(
    const float* __restrict__ hnew, const float* __restrict__ sh,
    const float* __restrict__ v,       // [B*S, 100] = selu(enc) @ Wf2^T
    const float* __restrict__ W_fuse,  // rows n: W_fuse[n, :H] (the out-part)
    const float* __restrict__ b_fuse,
    const float* __restrict__ W_copy, const float* __restrict__ b_copy,
    const float* __restrict__ We, const float* __restrict__ be,
    const int* __restrict__ sentence, const float* __restrict__ word_emb,
    float* __restrict__ out_copy, int slot,
    float* __restrict__ emb, float* __restrict__ out_act, int aslot)
{
    __shared__ float u_lds[100];       // u[n] + b_fuse[n]
    __shared__ float sco[101];
    __shared__ int   act_sh;
    const int b = blockIdx.x, t = threadIdx.x;
    const int wv = t >> 6, ln = t & 63;
    const float* shb = sh + (size_t)b * H;
    // u[n] = sh[b] . W_fuse[n, :H]   (n = wv, wv+4, ...)
    for (int n = wv; n < 100; n += 4){
        const float* wr = W_fuse + (size_t)n * (2*H);
        float a = 0.f;
        #pragma unroll
        for (int uu = 0; uu < H/64; ++uu) a += shb[ln + 64*uu] * wr[ln + 64*uu];
        a = wred_sum(a);
        if (ln == 0) u_lds[n] = a + b_fuse[n];
    }
    // eos = hnew[b] . We + be   (wave 0 extra duty; separate from u-loop scheduling)
    if (wv == 3){
        const float* hr = hnew + (size_t)b * H;
        float a = 0.f;
        #pragma unroll
        for (int uu = 0; uu < H/64; ++uu) a += hr[ln + 64*uu] * We[ln + 64*uu];
        a = wred_sum(a);
        if (ln == 0) sco[100] = a + be[0];
    }
    __syncthreads();
    // scores: sco[s] = sum_n selu(u[n] + v[b*S+s, n]) * W_copy[n] + b_copy
    const float bc = b_copy[0];
    for (int s = wv; s < S; s += 4){
        const float* vb = v + ((size_t)b * S + s) * 100;
        float a = 0.f;
        if (ln < 100)      a += selu_f(u_lds[ln]      + vb[ln])      * W_copy[ln];
        if (ln + 64 < 100) a += selu_f(u_lds[ln + 64] + vb[ln + 64]) * W_copy[ln + 64];
        a = wred_sum(a);
        if (ln == 0) sco[s] = a + bc;
    }
    __syncthreads();
    if (wv == 0){
        const float v1 = sco[ln];
        const int i2 = ln + 64;
        const float v2 = (i2 <= S) ? sco[i2] : -INFINITY;
        const float m = wred_maxf(fmaxf(v1, v2));
        const float p1 = v1 - m, p2 = v2 - m;
        float e = expf(p1) + ((i2 <= S) ? expf(p2) : 0.f);
        const float lse = logf(wred_sum(e));
        const float q1 = p1 - lse, q2 = p2 - lse;
        float bv; int bi;
        if (q2 > q1){ bv = q2; bi = i2; } else { bv = q1; bi = ln; }
        #pragma unroll
        for (int o = 32; o > 0; o >>= 1){
            float ov = __shfl_xor(bv, o);
            int   oi = __shfl_xor(bi, o);
            if (ov > bv || (ov == bv && oi < bi)){ bv = ov; bi = oi; }
        }
        const size_t obase = (size_t)slot * B * (S+1) + (size_t)b * (S+1);
        out_copy[obase + ln] = q1;
        if (i2 <= S) out_copy[obase + i2] = q2;
        if (ln == 0){
            out_act[(size_t)aslot * B + b] = (float)bi;
            act_sh = bi;
        }
    }
    __syncthreads();
    const int act = act_sh;
    const int wd = sentence[b * S + (act < S ? act : S - 1)];
    const float* wr = word_emb + (size_t)wd * E;
    float* ebp = emb + (size_t)b * E;
    #pragma unroll
    for (int u = 0; u < 2; ++u) ebp[t + 256*u] = wr[t + 256*u];
}

extern "C" void kernel_launch(void* const* d_in, const int* in_sizes, int n_in,
                              void* d_out, int out_size, void* d_ws, size_t ws_size,
                              hipStream_t stream)
{
    (void)in_sizes; (void)n_in; (void)out_size; (void)ws_size;
    const int*   sentence = (const int*)  d_in[0];
    const float* dec      = (const float*)d_in[1];
    const float* enc      = (const float*)d_in[2];
    const float* word_emb = (const float*)d_in[3];
    const float* rel_emb  = (const float*)d_in[4];
    const float* sos      = (const float*)d_in[5];
    const float* W_comb   = (const float*)d_in[6];
    const float* b_comb   = (const float*)d_in[7];
    const float* W_attn   = (const float*)d_in[8];
    // d_in[9] = b_attn (cancels in softmax)
    const float* W_ih     = (const float*)d_in[10];
    const float* W_hh     = (const float*)d_in[11];
    const float* b_ih     = (const float*)d_in[12];
    const float* b_hh     = (const float*)d_in[13];
    const float* W_eos    = (const float*)d_in[14];
    const float* b_eos    = (const float*)d_in[15];
    const float* W_pred   = (const float*)d_in[16];
    const float* b_pred   = (const float*)d_in[17];
    const float* W_fuse   = (const float*)d_in[18];
    const float* b_fuse   = (const float*)d_in[19];
    const float* W_copy   = (const float*)d_in[20];
    const float* b_copy   = (const float*)d_in[21];

    // OUTPUT IS FLOAT32
    float* out       = (float*)d_out;
    float* out_rel   = out;
    float* out_copy  = out + (size_t)NC * B * (R + 1);
    float* out_act   = out_copy + (size_t)2 * NC * B * (S + 1);

    float* p = (float*)d_ws;
    float* v_buf = p; p += (size_t)B * S * 100;   // 2.56M floats
    float* ctx   = p; p += B * H;
    float* xc    = p; p += B * E;
    float* emb   = p; p += B * E;
    float* hb0   = p; p += B * H;
    float* hb1   = p; p += B * H;
    float* sh    = p; p += B * H;
    float* xbuf  = p; p += B * E;
    float* gi    = p; p += B * 3 * H;
    float* gh    = p; p += B * 3 * H;
    float* hb[2] = { hb0, hb1 };

    // ---- loop-invariant precompute ----
    k_ctx<<<B, 256, 0, stream>>>(enc, W_attn, ctx);
    // xc = ctx @ Wc2^T + b_comb
    k_gemm<<<dim3(E/64, B/64), 256, 0, stream>>>(ctx, H, W_comb + E, H + E,
                                                 b_comb, nullptr, xc, E, E, H, 0);
    // v = selu(enc) @ Wf2^T   (25600 x 100, K=512)
    k_gemm<<<dim3(2, (B*S)/64), 256, 0, stream>>>(enc, H, W_fuse + H, 2*H,
                                                  nullptr, nullptr, v_buf, 100, 100, H, 1);
    k_emb_init<<<(B*E)/256, 256, 0, stream>>>(sos, emb);

    int cur = 0;
    for (int c = 0; c < NC; ++c){
        if (c == 0){
            k_hinit<<<(B*H)/256, 256, 0, stream>>>(dec, nullptr, hb[0]);
            cur = 0;
        } else {
            k_hinit<<<(B*H)/256, 256, 0, stream>>>(dec, hb[cur], hb[cur^1]);
            cur ^= 1;
        }
        for (int t3 = 0; t3 < 3; ++t3){
            // x = emb @ Wc1^T + xc
            k_gemm<<<dim3(E/64, B/64), 256, 0, stream>>>(emb, E, W_comb, H + E,
                                                         nullptr, xc, xbuf, E, E, E, 0);
            k_gru_gemm<<<dim3(2*3*H/64, B/64), 256, 0, stream>>>(
                xbuf, hb[cur],
                W_ih + (size_t)c * 3 * H * E, W_hh + (size_t)c * 3 * H * H,
                b_ih + (size_t)c * 3 * H,     b_hh + (size_t)c * 3 * H,
                gi, gh);
            k_combine<<<(B*H)/256, 256, 0, stream>>>(gi, gh, hb[cur], hb[cur^1], sh);
            cur ^= 1;
            if (t3 == 0){
                k_rel_step<<<B, 256, 0, stream>>>(hb[cur], W_pred, b_pred,
                                                  W_eos, b_eos, rel_emb,
                                                  out_rel, c, emb, out_act);
            } else {
                k_copy_step<<<B, 256, 0, stream>>>(hb[cur], sh, v_buf,
                                                   W_fuse, b_fuse, W_copy, b_copy,
                                                   W_eos, b_eos, sentence, word_emb,
                                                   out_copy, 2*c + (t3-1),
                                                   emb, out_act, 3*c + t3);
            }
        }
    }
}

// Round 7
// 1625.788 us; speedup vs baseline: 4.0112x; 1.2736x over previous
//
#include <hip/hip_runtime.h>
#include <math.h>

#define B 256
#define S 100
#define H 512
#define E 512
#define R 50
#define NC 5
#define H3 1536

__device__ __forceinline__ float selu_f(float x){
    return x > 0.0f ? 1.0507009873554805f * x
                    : 1.7580993408473766f * expm1f(x);   // scale*alpha
}
__device__ __forceinline__ float wred_sum(float v){
    #pragma unroll
    for (int o = 32; o > 0; o >>= 1) v += __shfl_xor(v, o);
    return v;
}
__device__ __forceinline__ float wred_maxf(float v){
    #pragma unroll
    for (int o = 32; o > 0; o >>= 1) v = fmaxf(v, __shfl_xor(v, o));
    return v;
}

// ================= double-buffered tiled f32 GEMM =================
// C[M,N] = (seluA? selu(A) : A)[M,K] @ W[N,:K]^T (+bias[n]) (+addm[m,n])
struct GemmSmem {
    float As[2][16][65];
    float Ws[2][16][65];
};

__device__ __forceinline__ void gemm_dbuf(
    GemmSmem& sm,
    const float* __restrict__ A, int lda,
    const float* __restrict__ W, int ldw,
    const float* __restrict__ bias,
    const float* __restrict__ addm, int ldadd,
    float* __restrict__ C, int ldc,
    int N, int K, int m0, int n0, int seluA)
{
    const int t = threadIdx.x;
    const int tx = t & 15, ty = t >> 4;
    const int lm = t >> 2, lk = (t & 3) << 2;
    const float* Ap = A + (size_t)(m0 + lm) * lda + lk;
    const int nw = n0 + lm;
    const float* Wp = W + (size_t)nw * ldw + lk;
    const bool wok = (nw < N);

    float4 a = *(const float4*)Ap;
    if (seluA){ a.x = selu_f(a.x); a.y = selu_f(a.y); a.z = selu_f(a.z); a.w = selu_f(a.w); }
    float4 w = wok ? *(const float4*)Wp : make_float4(0.f, 0.f, 0.f, 0.f);
    sm.As[0][lk  ][lm] = a.x; sm.As[0][lk+1][lm] = a.y;
    sm.As[0][lk+2][lm] = a.z; sm.As[0][lk+3][lm] = a.w;
    sm.Ws[0][lk  ][lm] = w.x; sm.Ws[0][lk+1][lm] = w.y;
    sm.Ws[0][lk+2][lm] = w.z; sm.Ws[0][lk+3][lm] = w.w;
    __syncthreads();

    float acc[4][4] = {};
    int cur = 0;
    for (int k0 = 16; k0 <= K; k0 += 16){
        const bool more = (k0 < K);
        if (more){
            a = *(const float4*)(Ap + k0);
            if (seluA){ a.x = selu_f(a.x); a.y = selu_f(a.y); a.z = selu_f(a.z); a.w = selu_f(a.w); }
            w = wok ? *(const float4*)(Wp + k0) : make_float4(0.f, 0.f, 0.f, 0.f);
        }
        #pragma unroll
        for (int kk = 0; kk < 16; ++kk){
            float a0 = sm.As[cur][kk][ty*4+0], a1 = sm.As[cur][kk][ty*4+1];
            float a2 = sm.As[cur][kk][ty*4+2], a3 = sm.As[cur][kk][ty*4+3];
            float b0 = sm.Ws[cur][kk][tx*4+0], b1 = sm.Ws[cur][kk][tx*4+1];
            float b2 = sm.Ws[cur][kk][tx*4+2], b3 = sm.Ws[cur][kk][tx*4+3];
            acc[0][0] += a0*b0; acc[0][1] += a0*b1; acc[0][2] += a0*b2; acc[0][3] += a0*b3;
            acc[1][0] += a1*b0; acc[1][1] += a1*b1; acc[1][2] += a1*b2; acc[1][3] += a1*b3;
            acc[2][0] += a2*b0; acc[2][1] += a2*b1; acc[2][2] += a2*b2; acc[2][3] += a2*b3;
            acc[3][0] += a3*b0; acc[3][1] += a3*b1; acc[3][2] += a3*b2; acc[3][3] += a3*b3;
        }
        if (more){
            const int nx = cur ^ 1;
            sm.As[nx][lk  ][lm] = a.x; sm.As[nx][lk+1][lm] = a.y;
            sm.As[nx][lk+2][lm] = a.z; sm.As[nx][lk+3][lm] = a.w;
            sm.Ws[nx][lk  ][lm] = w.x; sm.Ws[nx][lk+1][lm] = w.y;
            sm.Ws[nx][lk+2][lm] = w.z; sm.Ws[nx][lk+3][lm] = w.w;
            __syncthreads();
            cur = nx;
        }
    }
    #pragma unroll
    for (int i = 0; i < 4; ++i){
        const int m = m0 + ty*4 + i;
        #pragma unroll
        for (int j = 0; j < 4; ++j){
            const int n = n0 + tx*4 + j;
            if (n < N){
                float vv = acc[i][j];
                if (bias) vv += bias[n];
                if (addm) vv += addm[(size_t)m * ldadd + n];
                C[(size_t)m * ldc + n] = vv;
            }
        }
    }
}

// batched (z) generic GEMM
__global__ __launch_bounds__(256) void k_gemm(
    const float* A, int lda, long long sA,
    const float* W, int ldw, long long sW,
    const float* bias, long long sBias,
    const float* addm, int ldadd, long long sAddm,
    float* C, int ldc, long long sC,
    int N, int K, int seluA)
{
    __shared__ GemmSmem sm;
    const int z = blockIdx.z;
    gemm_dbuf(sm,
              A + (size_t)z * sA, lda,
              W + (size_t)z * sW, ldw,
              bias ? bias + (size_t)z * sBias : nullptr,
              addm ? addm + (size_t)z * sAddm : nullptr, ldadd,
              C + (size_t)z * sC, ldc,
              N, K, blockIdx.y * 64, blockIdx.x * 64, seluA);
}

// per-step GEMM: gi = emb @ Wihc^T + gixc ; gh = h @ Whh^T + bhh (one launch)
__global__ __launch_bounds__(256) void k_gru2(
    const float* emb, const float* h,
    const float* Wihc, const float* Whh,
    const float* gixc, const float* bhh,
    float* gi, float* gh)
{
    __shared__ GemmSmem sm;
    const int n0 = blockIdx.x * 64;
    if (n0 < H3)
        gemm_dbuf(sm, emb, E, Wihc, E, nullptr, gixc, H3, gi, H3,
                  H3, E, blockIdx.y * 64, n0, 0);
    else
        gemm_dbuf(sm, h, H, Whh, H, bhh, nullptr, 0, gh, H3,
                  H3, H, blockIdx.y * 64, n0 - H3, 0);
}

// ================= attention context (loop-invariant) =================
__global__ __launch_bounds__(256) void k_ctx(const float* __restrict__ enc,
                                             const float* __restrict__ W_attn,
                                             float* __restrict__ ctx)
{
    __shared__ float sc[128];
    __shared__ float red[128];
    const int b = blockIdx.x;
    const int t = threadIdx.x;
    const int wv = t >> 6, ln = t & 63;
    const float* eb = enc + (size_t)b * S * H;
    const float* wa = W_attn + H;
    for (int s = wv; s < S; s += 4){
        const float* es = eb + (size_t)s * H;
        float a = 0.f;
        #pragma unroll
        for (int u = 0; u < H/64; ++u) a += es[ln + 64*u] * wa[ln + 64*u];
        a = wred_sum(a);
        if (ln == 0) sc[s] = a;
    }
    __syncthreads();
    float vm = (t < S) ? sc[t] : -INFINITY;
    if (t < 128) red[t] = vm;
    __syncthreads();
    for (int st = 64; st > 0; st >>= 1){
        if (t < st) red[t] = fmaxf(red[t], red[t + st]);
        __syncthreads();
    }
    const float m = red[0];
    __syncthreads();
    float e = (t < S) ? expf(sc[t] - m) : 0.f;
    if (t < 128) red[t] = e;
    __syncthreads();
    for (int st = 64; st > 0; st >>= 1){
        if (t < st) red[t] += red[t + st];
        __syncthreads();
    }
    const float sum = red[0];
    __syncthreads();
    if (t < S) sc[t] = e / sum;
    __syncthreads();
    for (int hh = t; hh < H; hh += 256){
        float a = 0.f;
        for (int s = 0; s < S; ++s) a += sc[s] * eb[(size_t)s * H + hh];
        ctx[(size_t)b * H + hh] = a;
    }
}

// ================= Wc1^T (for the Wihc fold) =================
__global__ __launch_bounds__(256) void k_transpose(const float* __restrict__ Wc,
                                                   float* __restrict__ WT)
{
    __shared__ float tile[64][65];
    const int bx = blockIdx.x * 64;   // k range
    const int by = blockIdx.y * 64;   // j range
    const int t = threadIdx.x;
    const int c4 = (t & 15) * 4, rg = t >> 4;
    for (int r = 0; r < 64; r += 16){
        float4 v = *(const float4*)(Wc + (size_t)(by + rg + r) * (H + E) + bx + c4);
        tile[rg + r][c4+0] = v.x; tile[rg + r][c4+1] = v.y;
        tile[rg + r][c4+2] = v.z; tile[rg + r][c4+3] = v.w;
    }
    __syncthreads();
    for (int r = 0; r < 64; r += 16){
        float4 v;
        v.x = tile[c4+0][rg + r]; v.y = tile[c4+1][rg + r];
        v.z = tile[c4+2][rg + r]; v.w = tile[c4+3][rg + r];
        // WT[k][j] = Wc[j][k]; here row = bx + rg + r ... wrong pairing; write per-element
        WT[(size_t)(bx + rg + r) * E + by + c4 + 0] = tile[c4+0][rg + r];
        WT[(size_t)(bx + rg + r) * E + by + c4 + 1] = tile[c4+1][rg + r];
        WT[(size_t)(bx + rg + r) * E + by + c4 + 2] = tile[c4+2][rg + r];
        WT[(size_t)(bx + rg + r) * E + by + c4 + 3] = tile[c4+3][rg + r];
        (void)v;
    }
}

// ================= init: emb = sos, h0 = 0.5*dec =================
__global__ __launch_bounds__(256) void k_init(
    const float* __restrict__ sos, const float* __restrict__ dec,
    float* __restrict__ emb, float* __restrict__ h0)
{
    const int idx = blockIdx.x * 256 + threadIdx.x;   // B*E == B*H
    emb[idx] = sos[idx & (E - 1)];
    h0[idx]  = 0.5f * dec[idx];
}

// ================= fused rel step: GRU combine + 51 logits + softmax + argmax + gather ==========
__global__ __launch_bounds__(256) void k_rel_fused(
    const float* __restrict__ gi, const float* __restrict__ gh,
    const float* __restrict__ hold,
    const float* __restrict__ Wp, const float* __restrict__ bp,
    const float* __restrict__ We, const float* __restrict__ be,
    const float* __restrict__ rel_emb,
    float* __restrict__ out_rel, int c,
    float* __restrict__ emb, float* __restrict__ out_act,
    float* __restrict__ hnew_out)
{
    __shared__ float hn[H];
    __shared__ float logits[R + 1];
    __shared__ int   act_sh;
    const int b = blockIdx.x, t = threadIdx.x;
    const int wvi = t >> 6, ln = t & 63;
    const size_t gbase = (size_t)b * H3;
    for (int g = t; g < H; g += 256){
        const float ir  = gi[gbase + g],         hr  = gh[gbase + g];
        const float iz  = gi[gbase + H + g],     hz  = gh[gbase + H + g];
        const float in_ = gi[gbase + 2*H + g],   hnn = gh[gbase + 2*H + g];
        const float r = 1.f / (1.f + expf(-(ir + hr)));
        const float z = 1.f / (1.f + expf(-(iz + hz)));
        const float n = tanhf(in_ + r * hnn);
        const float hv = (1.f - z) * n + z * hold[(size_t)b * H + g];
        hn[g] = hv;
        hnew_out[(size_t)b * H + g] = hv;
    }
    __syncthreads();
    for (int i = wvi; i < R + 1; i += 4){
        const float* wr = (i < R) ? Wp + (size_t)i * H : We;
        float a = 0.f;
        #pragma unroll
        for (int u = 0; u < H/64; ++u) a += hn[ln + 64*u] * wr[ln + 64*u];
        a = wred_sum(a);
        if (ln == 0) logits[i] = a + (i < R ? bp[i] : be[0]);
    }
    __syncthreads();
    if (wvi == 0){
        const float v = (ln < R + 1) ? logits[ln] : -INFINITY;
        const float m = wred_maxf(v);
        const float p = v - m;
        const float e = (ln < R + 1) ? expf(p) : 0.f;
        const float lse = logf(wred_sum(e));
        const float q = p - lse;
        float bv = q; int bi = ln;
        #pragma unroll
        for (int o = 32; o > 0; o >>= 1){
            float ov = __shfl_xor(bv, o);
            int   oi = __shfl_xor(bi, o);
            if (ov > bv || (ov == bv && oi < bi)){ bv = ov; bi = oi; }
        }
        if (ln < R + 1)
            out_rel[(size_t)c * B * (R+1) + (size_t)b * (R+1) + ln] = q;
        if (ln == 0){
            out_act[(size_t)(3*c) * B + b] = (float)bi;
            act_sh = bi;
        }
    }
    __syncthreads();
    const float* er = rel_emb + (size_t)act_sh * E;
    float* ebp = emb + (size_t)b * E;
    ebp[t] = er[t];
    ebp[t + 256] = er[t + 256];
}

// ===== fused copy step: GRU combine + eos + u-dots + 100 scores + softmax(101) + argmax + gather
__global__ __launch_bounds__(256) void k_copy_fused(
    const float* __restrict__ gi, const float* __restrict__ gh,
    const float* __restrict__ hold,
    const float* __restrict__ v,       // [B*S,100] = selu(enc)@Wf2^T
    const float* __restrict__ W_fuse, const float* __restrict__ b_fuse,
    const float* __restrict__ W_copy, const float* __restrict__ b_copy,
    const float* __restrict__ We, const float* __restrict__ be,
    const int* __restrict__ sentence, const float* __restrict__ word_emb,
    float* __restrict__ out_copy, int slot,
    float* __restrict__ emb, float* __restrict__ out_act, int aslot,
    float* __restrict__ hnew_out, const float* __restrict__ dec, int cell_end)
{
    __shared__ float hn[H];
    __shared__ float shl[H];
    __shared__ float u_lds[100];
    __shared__ float wc_lds[100];
    __shared__ float sco[101];
    __shared__ int   act_sh;
    const int b = blockIdx.x, t = threadIdx.x;
    const int wvi = t >> 6, ln = t & 63;
    const size_t gbase = (size_t)b * H3;
    for (int g = t; g < H; g += 256){
        const float ir  = gi[gbase + g],         hr  = gh[gbase + g];
        const float iz  = gi[gbase + H + g],     hz  = gh[gbase + H + g];
        const float in_ = gi[gbase + 2*H + g],   hnn = gh[gbase + 2*H + g];
        const float r = 1.f / (1.f + expf(-(ir + hr)));
        const float z = 1.f / (1.f + expf(-(iz + hz)));
        const float n = tanhf(in_ + r * hnn);
        const float hv = (1.f - z) * n + z * hold[(size_t)b * H + g];
        hn[g] = hv;
        shl[g] = selu_f(hv);
        hnew_out[(size_t)b * H + g] = cell_end ? 0.5f * (dec[(size_t)b * H + g] + hv) : hv;
    }
    if (t < 100) wc_lds[t] = W_copy[t];
    __syncthreads();
    for (int n = wvi; n < 100; n += 4){
        const float* wr = W_fuse + (size_t)n * (2*H);
        float a = 0.f;
        #pragma unroll
        for (int u = 0; u < H/64; ++u) a += shl[ln + 64*u] * wr[ln + 64*u];
        a = wred_sum(a);
        if (ln == 0) u_lds[n] = a + b_fuse[n];
    }
    if (wvi == 3){
        float a = 0.f;
        #pragma unroll
        for (int u = 0; u < H/64; ++u) a += hn[ln + 64*u] * We[ln + 64*u];
        a = wred_sum(a);
        if (ln == 0) sco[100] = a + be[0];
    }
    __syncthreads();
    const float bc = b_copy[0];
    for (int s = wvi; s < S; s += 4){
        const float* vb = v + ((size_t)b * S + s) * 100;
        float a = selu_f(u_lds[ln] + vb[ln]) * wc_lds[ln];
        if (ln + 64 < 100) a += selu_f(u_lds[ln + 64] + vb[ln + 64]) * wc_lds[ln + 64];
        a = wred_sum(a);
        if (ln == 0) sco[s] = a + bc;
    }
    __syncthreads();
    if (wvi == 0){
        const float v1 = sco[ln];
        const int i2 = ln + 64;
        const float v2 = (i2 <= S) ? sco[i2] : -INFINITY;
        const float m = wred_maxf(fmaxf(v1, v2));
        const float p1 = v1 - m, p2 = v2 - m;
        float e = expf(p1) + ((i2 <= S) ? expf(p2) : 0.f);
        const float lse = logf(wred_sum(e));
        const float q1 = p1 - lse, q2 = p2 - lse;
        float bv; int bi;
        if (q2 > q1){ bv = q2; bi = i2; } else { bv = q1; bi = ln; }
        #pragma unroll
        for (int o = 32; o > 0; o >>= 1){
            float ov = __shfl_xor(bv, o);
            int   oi = __shfl_xor(bi, o);
            if (ov > bv || (ov == bv && oi < bi)){ bv = ov; bi = oi; }
        }
        const size_t obase = (size_t)slot * B * (S+1) + (size_t)b * (S+1);
        out_copy[obase + ln] = q1;
        if (i2 <= S) out_copy[obase + i2] = q2;
        if (ln == 0){
            out_act[(size_t)aslot * B + b] = (float)bi;
            act_sh = bi;
        }
    }
    __syncthreads();
    const int act = act_sh;
    const int wd = sentence[b * S + (act < S ? act : S - 1)];
    const float* wr = word_emb + (size_t)wd * E;
    float* ebp = emb + (size_t)b * E;
    ebp[t] = wr[t];
    ebp[t + 256] = wr[t + 256];
}

extern "C" void kernel_launch(void* const* d_in, const int* in_sizes, int n_in,
                              void* d_out, int out_size, void* d_ws, size_t ws_size,
                              hipStream_t stream)
{
    (void)in_sizes; (void)n_in; (void)out_size; (void)ws_size;
    const int*   sentence = (const int*)  d_in[0];
    const float* dec      = (const float*)d_in[1];
    const float* enc      = (const float*)d_in[2];
    const float* word_emb = (const float*)d_in[3];
    const float* rel_emb  = (const float*)d_in[4];
    const float* sos      = (const float*)d_in[5];
    const float* W_comb   = (const float*)d_in[6];
    const float* b_comb   = (const float*)d_in[7];
    const float* W_attn   = (const float*)d_in[8];
    // d_in[9] = b_attn (cancels in softmax)
    const float* W_ih     = (const float*)d_in[10];
    const float* W_hh     = (const float*)d_in[11];
    const float* b_ih     = (const float*)d_in[12];
    const float* b_hh     = (const float*)d_in[13];
    const float* W_eos    = (const float*)d_in[14];
    const float* b_eos    = (const float*)d_in[15];
    const float* W_pred   = (const float*)d_in[16];
    const float* b_pred   = (const float*)d_in[17];
    const float* W_fuse   = (const float*)d_in[18];
    const float* b_fuse   = (const float*)d_in[19];
    const float* W_copy   = (const float*)d_in[20];
    const float* b_copy   = (const float*)d_in[21];

    float* out       = (float*)d_out;
    float* out_rel   = out;
    float* out_copy  = out + (size_t)NC * B * (R + 1);
    float* out_act   = out_copy + (size_t)2 * NC * B * (S + 1);

    float* p = (float*)d_ws;
    float* v_buf = p; p += (size_t)B * S * 100;       // 2.56M
    float* Wihc  = p; p += (size_t)NC * H3 * E;       // 3.93M
    float* gixc  = p; p += (size_t)NC * B * H3;       // 1.97M
    float* Wc1T  = p; p += (size_t)E * E;             // 0.26M
    float* ctx   = p; p += B * H;
    float* xc    = p; p += B * E;
    float* emb   = p; p += B * E;
    float* hb0   = p; p += B * H;
    float* hb1   = p; p += B * H;
    float* gi    = p; p += (size_t)B * H3;
    float* gh    = p; p += (size_t)B * H3;
    float* hb[2] = { hb0, hb1 };

    // ---- one-time precompute ----
    k_init<<<(B*E)/256, 256, 0, stream>>>(sos, dec, emb, hb0);
    k_ctx<<<B, 256, 0, stream>>>(enc, W_attn, ctx);
    // xc = ctx @ Wc2^T + b_comb
    k_gemm<<<dim3(E/64, B/64, 1), 256, 0, stream>>>(
        ctx, H, 0, W_comb + E, H + E, 0, b_comb, 0,
        nullptr, 0, 0, xc, E, 0, E, H, 0);
    // Wc1^T
    k_transpose<<<dim3(8, 8), 256, 0, stream>>>(W_comb, Wc1T);
    // Wihc[c] = W_ih[c] @ Wc1   (batched z=5)
    k_gemm<<<dim3(E/64, H3/64, NC), 256, 0, stream>>>(
        W_ih, E, (long long)H3 * E, Wc1T, E, 0, nullptr, 0,
        nullptr, 0, 0, Wihc, E, (long long)H3 * E, E, E, 0);
    // gixc[c] = xc @ W_ih[c]^T + b_ih[c]   (batched z=5)
    k_gemm<<<dim3(H3/64, B/64, NC), 256, 0, stream>>>(
        xc, E, 0, W_ih, E, (long long)H3 * E, b_ih, H3,
        nullptr, 0, 0, gixc, H3, (long long)B * H3, H3, E, 0);
    // v = selu(enc) @ Wf2^T
    k_gemm<<<dim3(2, (B*S)/64, 1), 256, 0, stream>>>(
        enc, H, 0, W_fuse + H, 2*H, 0, nullptr, 0,
        nullptr, 0, 0, v_buf, 100, 0, 100, H, 1);

    int cur = 0;
    for (int c = 0; c < NC; ++c){
        for (int t3 = 0; t3 < 3; ++t3){
            k_gru2<<<dim3(2*H3/64, B/64), 256, 0, stream>>>(
                emb, hb[cur],
                Wihc + (size_t)c * H3 * E, W_hh + (size_t)c * H3 * H,
                gixc + (size_t)c * B * H3, b_hh + (size_t)c * H3,
                gi, gh);
            if (t3 == 0){
                k_rel_fused<<<B, 256, 0, stream>>>(
                    gi, gh, hb[cur], W_pred, b_pred, W_eos, b_eos, rel_emb,
                    out_rel, c, emb, out_act, hb[cur^1]);
            } else {
                k_copy_fused<<<B, 256, 0, stream>>>(
                    gi, gh, hb[cur], v_buf, W_fuse, b_fuse, W_copy, b_copy,
                    W_eos, b_eos, sentence, word_emb,
                    out_copy, 2*c + (t3-1), emb, out_act, 3*c + t3,
                    hb[cur^1], dec, (t3 == 2) ? 1 : 0);
            }
            cur ^= 1;
        }
    }
}

// Round 8
// 1408.868 us; speedup vs baseline: 4.6288x; 1.1540x over previous
//
#include <hip/hip_runtime.h>
#include <math.h>

#define B 256
#define S 100
#define H 512
#define E 512
#define R 50
#define NC 5
#define H3 1536

__device__ __forceinline__ float selu_f(float x){
    return x > 0.0f ? 1.0507009873554805f * x
                    : 1.7580993408473766f * expm1f(x);   // scale*alpha
}
__device__ __forceinline__ float wred_sum(float v){
    #pragma unroll
    for (int o = 32; o > 0; o >>= 1) v += __shfl_xor(v, o);
    return v;
}
__device__ __forceinline__ float wred_maxf(float v){
    #pragma unroll
    for (int o = 32; o > 0; o >>= 1) v = fmaxf(v, __shfl_xor(v, o));
    return v;
}

// ============== 64x128 tiled f32 GEMM, 4x8/thread, float4 LDS reads ==============
// C[M,N](+=k-range) = (seluA? selu(A) : A)[M,K] @ W[N,:K]^T (+bias[n]) (+addm[m,n])
struct GSmem {
    alignas(16) float As[16][68];    // [k][m]
    alignas(16) float Ws[16][132];   // [k][n]
};

__device__ __forceinline__ void gemm_64x128(
    GSmem& sm,
    const float* __restrict__ A, int lda,
    const float* __restrict__ W, int ldw,
    const float* __restrict__ bias,
    const float* __restrict__ addm, int ldadd,
    float* __restrict__ C, int ldc,
    int N, int m0, int n0, int k0beg, int k0end, int seluA)
{
    const int t  = threadIdx.x;
    const int tx = t & 15;            // n-group (8 cols)
    const int ty = t >> 4;            // m-group (4 rows)
    const int lm = t >> 2,  lk  = (t & 3) << 2;   // A loader
    const int lw = t >> 1,  lkw = (t & 1) << 3;   // W loader
    const float* Ap = A + (size_t)(m0 + lm) * lda + lk;
    const int nw = n0 + lw;
    const float* Wp = W + (size_t)nw * ldw + lkw;
    const bool wok = (nw < N);
    const float4 f40 = make_float4(0.f, 0.f, 0.f, 0.f);

    float4 ar = *(const float4*)(Ap + k0beg);
    if (seluA){ ar.x = selu_f(ar.x); ar.y = selu_f(ar.y); ar.z = selu_f(ar.z); ar.w = selu_f(ar.w); }
    float4 w0 = wok ? *(const float4*)(Wp + k0beg)     : f40;
    float4 w1 = wok ? *(const float4*)(Wp + k0beg + 4) : f40;

    float acc[4][8] = {};
    for (int k0 = k0beg; k0 < k0end; k0 += 16){
        if (k0 != k0beg) __syncthreads();
        sm.As[lk+0][lm] = ar.x; sm.As[lk+1][lm] = ar.y;
        sm.As[lk+2][lm] = ar.z; sm.As[lk+3][lm] = ar.w;
        sm.Ws[lkw+0][lw] = w0.x; sm.Ws[lkw+1][lw] = w0.y;
        sm.Ws[lkw+2][lw] = w0.z; sm.Ws[lkw+3][lw] = w0.w;
        sm.Ws[lkw+4][lw] = w1.x; sm.Ws[lkw+5][lw] = w1.y;
        sm.Ws[lkw+6][lw] = w1.z; sm.Ws[lkw+7][lw] = w1.w;
        __syncthreads();
        if (k0 + 16 < k0end){
            ar = *(const float4*)(Ap + k0 + 16);
            if (seluA){ ar.x = selu_f(ar.x); ar.y = selu_f(ar.y); ar.z = selu_f(ar.z); ar.w = selu_f(ar.w); }
            w0 = wok ? *(const float4*)(Wp + k0 + 16)     : f40;
            w1 = wok ? *(const float4*)(Wp + k0 + 16 + 4) : f40;
        }
        #pragma unroll
        for (int kk = 0; kk < 16; ++kk){
            const float4 av  = *(const float4*)&sm.As[kk][ty*4];
            const float4 wv0 = *(const float4*)&sm.Ws[kk][tx*8];
            const float4 wv1 = *(const float4*)&sm.Ws[kk][tx*8+4];
            const float aa[4] = {av.x, av.y, av.z, av.w};
            const float bb[8] = {wv0.x, wv0.y, wv0.z, wv0.w, wv1.x, wv1.y, wv1.z, wv1.w};
            #pragma unroll
            for (int i = 0; i < 4; ++i)
                #pragma unroll
                for (int j = 0; j < 8; ++j)
                    acc[i][j] += aa[i] * bb[j];
        }
    }
    #pragma unroll
    for (int i = 0; i < 4; ++i){
        const int m = m0 + ty*4 + i;
        #pragma unroll
        for (int j = 0; j < 8; ++j){
            const int n = n0 + tx*8 + j;
            if (n < N){
                float vv = acc[i][j];
                if (bias) vv += bias[n];
                if (addm) vv += addm[(size_t)m * ldadd + n];
                C[(size_t)m * ldc + n] = vv;
            }
        }
    }
}

// generic batched GEMM (full-K): grid (ceil(N/128), M/64, batch)
__global__ __launch_bounds__(256) void k_gemm(
    const float* A, int lda, long long sA,
    const float* W, int ldw, long long sW,
    const float* bias, long long sBias,
    const float* addm, int ldadd, long long sAddm,
    float* C, int ldc, long long sC,
    int N, int K, int seluA)
{
    __shared__ GSmem sm;
    const int z = blockIdx.z;
    gemm_64x128(sm,
                A + (size_t)z * sA, lda,
                W + (size_t)z * sW, ldw,
                bias ? bias + (size_t)z * sBias : nullptr,
                addm ? addm + (size_t)z * sAddm : nullptr, ldadd,
                C + (size_t)z * sC, ldc,
                N, blockIdx.y * 64, blockIdx.x * 128, 0, K, seluA);
}

// per-step GEMM, split-K=2: gi = emb@Wihc^T (+gixc, z0) ; gh = h@Whh^T (+bhh, z0)
// grid (24, 4, 2): x<12 -> gi n-tile, x>=12 -> gh n-tile; z = k-half
__global__ __launch_bounds__(256) void k_gru2(
    const float* emb, const float* h,
    const float* Wihc, const float* Whh,
    const float* gixc, const float* bhh,
    float* gi0, float* gi1, float* gh0, float* gh1)
{
    __shared__ GSmem sm;
    const int xt = blockIdx.x;
    const int m0 = blockIdx.y * 64;
    const int z  = blockIdx.z;
    const int kb = z * 256, ke = kb + 256;
    if (xt < 12){
        gemm_64x128(sm, emb, E, Wihc, E, nullptr,
                    (z == 0) ? gixc : nullptr, H3,
                    (z == 0) ? gi0 : gi1, H3,
                    H3, m0, xt * 128, kb, ke, 0);
    } else {
        gemm_64x128(sm, h, H, Whh, H,
                    (z == 0) ? bhh : nullptr, nullptr, 0,
                    (z == 0) ? gh0 : gh1, H3,
                    H3, m0, (xt - 12) * 128, kb, ke, 0);
    }
}

// ================= attention context (loop-invariant) =================
__global__ __launch_bounds__(256) void k_ctx(const float* __restrict__ enc,
                                             const float* __restrict__ W_attn,
                                             float* __restrict__ ctx)
{
    __shared__ float sc[128];
    __shared__ float red[128];
    const int b = blockIdx.x;
    const int t = threadIdx.x;
    const int wv = t >> 6, ln = t & 63;
    const float* eb = enc + (size_t)b * S * H;
    const float* wa = W_attn + H;
    for (int s = wv; s < S; s += 4){
        const float* es = eb + (size_t)s * H;
        float a = 0.f;
        #pragma unroll
        for (int u = 0; u < H/64; ++u) a += es[ln + 64*u] * wa[ln + 64*u];
        a = wred_sum(a);
        if (ln == 0) sc[s] = a;
    }
    __syncthreads();
    float vm = (t < S) ? sc[t] : -INFINITY;
    if (t < 128) red[t] = vm;
    __syncthreads();
    for (int st = 64; st > 0; st >>= 1){
        if (t < st) red[t] = fmaxf(red[t], red[t + st]);
        __syncthreads();
    }
    const float m = red[0];
    __syncthreads();
    float e = (t < S) ? expf(sc[t] - m) : 0.f;
    if (t < 128) red[t] = e;
    __syncthreads();
    for (int st = 64; st > 0; st >>= 1){
        if (t < st) red[t] += red[t + st];
        __syncthreads();
    }
    const float sum = red[0];
    __syncthreads();
    if (t < S) sc[t] = e / sum;
    __syncthreads();
    for (int hh = t; hh < H; hh += 256){
        float a = 0.f;
        for (int s = 0; s < S; ++s) a += sc[s] * eb[(size_t)s * H + hh];
        ctx[(size_t)b * H + hh] = a;
    }
}

// ================= Wc1^T (for the Wihc fold) =================
__global__ __launch_bounds__(256) void k_transpose(const float* __restrict__ Wc,
                                                   float* __restrict__ WT)
{
    __shared__ float tile[64][65];
    const int bx = blockIdx.x * 64;   // k range
    const int by = blockIdx.y * 64;   // j range
    const int t = threadIdx.x;
    const int c4 = (t & 15) * 4, rg = t >> 4;
    for (int r = 0; r < 64; r += 16){
        float4 v = *(const float4*)(Wc + (size_t)(by + rg + r) * (H + E) + bx + c4);
        tile[rg + r][c4+0] = v.x; tile[rg + r][c4+1] = v.y;
        tile[rg + r][c4+2] = v.z; tile[rg + r][c4+3] = v.w;
    }
    __syncthreads();
    for (int r = 0; r < 64; r += 16){
        WT[(size_t)(bx + rg + r) * E + by + c4 + 0] = tile[c4+0][rg + r];
        WT[(size_t)(bx + rg + r) * E + by + c4 + 1] = tile[c4+1][rg + r];
        WT[(size_t)(bx + rg + r) * E + by + c4 + 2] = tile[c4+2][rg + r];
        WT[(size_t)(bx + rg + r) * E + by + c4 + 3] = tile[c4+3][rg + r];
    }
}

// ================= init: emb = sos, h0 = 0.5*dec =================
__global__ __launch_bounds__(256) void k_init(
    const float* __restrict__ sos, const float* __restrict__ dec,
    float* __restrict__ emb, float* __restrict__ h0)
{
    const int idx = blockIdx.x * 256 + threadIdx.x;
    emb[idx] = sos[idx & (E - 1)];
    h0[idx]  = 0.5f * dec[idx];
}

// ====== fused rel step: GRU combine(+splitK sum) + 51 logits + softmax + argmax + gather ======
__global__ __launch_bounds__(256) void k_rel_fused(
    const float* __restrict__ gi0, const float* __restrict__ gi1,
    const float* __restrict__ gh0, const float* __restrict__ gh1,
    const float* __restrict__ hold,
    const float* __restrict__ Wp, const float* __restrict__ bp,
    const float* __restrict__ We, const float* __restrict__ be,
    const float* __restrict__ rel_emb,
    float* __restrict__ out_rel, int c,
    float* __restrict__ emb, float* __restrict__ out_act,
    float* __restrict__ hnew_out)
{
    __shared__ float hn[H];
    __shared__ float logits[R + 1];
    __shared__ int   act_sh;
    const int b = blockIdx.x, t = threadIdx.x;
    const int wvi = t >> 6, ln = t & 63;
    const size_t gbase = (size_t)b * H3;
    for (int g = t; g < H; g += 256){
        const float ir  = gi0[gbase + g]       + gi1[gbase + g];
        const float hr  = gh0[gbase + g]       + gh1[gbase + g];
        const float iz  = gi0[gbase + H + g]   + gi1[gbase + H + g];
        const float hz  = gh0[gbase + H + g]   + gh1[gbase + H + g];
        const float in_ = gi0[gbase + 2*H + g] + gi1[gbase + 2*H + g];
        const float hnn = gh0[gbase + 2*H + g] + gh1[gbase + 2*H + g];
        const float r = 1.f / (1.f + expf(-(ir + hr)));
        const float z = 1.f / (1.f + expf(-(iz + hz)));
        const float n = tanhf(in_ + r * hnn);
        const float hv = (1.f - z) * n + z * hold[(size_t)b * H + g];
        hn[g] = hv;
        hnew_out[(size_t)b * H + g] = hv;
    }
    __syncthreads();
    for (int i = wvi; i < R + 1; i += 4){
        const float* wr = (i < R) ? Wp + (size_t)i * H : We;
        float a = 0.f;
        #pragma unroll
        for (int u = 0; u < H/64; ++u) a += hn[ln + 64*u] * wr[ln + 64*u];
        a = wred_sum(a);
        if (ln == 0) logits[i] = a + (i < R ? bp[i] : be[0]);
    }
    __syncthreads();
    if (wvi == 0){
        const float v = (ln < R + 1) ? logits[ln] : -INFINITY;
        const float m = wred_maxf(v);
        const float p = v - m;
        const float e = (ln < R + 1) ? expf(p) : 0.f;
        const float lse = logf(wred_sum(e));
        const float q = p - lse;
        float bv = q; int bi = ln;
        #pragma unroll
        for (int o = 32; o > 0; o >>= 1){
            float ov = __shfl_xor(bv, o);
            int   oi = __shfl_xor(bi, o);
            if (ov > bv || (ov == bv && oi < bi)){ bv = ov; bi = oi; }
        }
        if (ln < R + 1)
            out_rel[(size_t)c * B * (R+1) + (size_t)b * (R+1) + ln] = q;
        if (ln == 0){
            out_act[(size_t)(3*c) * B + b] = (float)bi;
            act_sh = bi;
        }
    }
    __syncthreads();
    const float* er = rel_emb + (size_t)act_sh * E;
    float* ebp = emb + (size_t)b * E;
    ebp[t] = er[t];
    ebp[t + 256] = er[t + 256];
}

// == fused copy step: GRU combine(+splitK) + eos + u-dots + scores + softmax(101) + argmax + gather
__global__ __launch_bounds__(256) void k_copy_fused(
    const float* __restrict__ gi0, const float* __restrict__ gi1,
    const float* __restrict__ gh0, const float* __restrict__ gh1,
    const float* __restrict__ hold,
    const float* __restrict__ v,       // [B*S,100] = selu(enc)@Wf2^T
    const float* __restrict__ W_fuse, const float* __restrict__ b_fuse,
    const float* __restrict__ W_copy, const float* __restrict__ b_copy,
    const float* __restrict__ We, const float* __restrict__ be,
    const int* __restrict__ sentence, const float* __restrict__ word_emb,
    float* __restrict__ out_copy, int slot,
    float* __restrict__ emb, float* __restrict__ out_act, int aslot,
    float* __restrict__ hnew_out, const float* __restrict__ dec, int cell_end)
{
    __shared__ float hn[H];
    __shared__ float shl[H];
    __shared__ float u_lds[100];
    __shared__ float wc_lds[100];
    __shared__ float sco[101];
    __shared__ int   act_sh;
    const int b = blockIdx.x, t = threadIdx.x;
    const int wvi = t >> 6, ln = t & 63;
    const size_t gbase = (size_t)b * H3;
    for (int g = t; g < H; g += 256){
        const float ir  = gi0[gbase + g]       + gi1[gbase + g];
        const float hr  = gh0[gbase + g]       + gh1[gbase + g];
        const float iz  = gi0[gbase + H + g]   + gi1[gbase + H + g];
        const float hz  = gh0[gbase + H + g]   + gh1[gbase + H + g];
        const float in_ = gi0[gbase + 2*H + g] + gi1[gbase + 2*H + g];
        const float hnn = gh0[gbase + 2*H + g] + gh1[gbase + 2*H + g];
        const float r = 1.f / (1.f + expf(-(ir + hr)));
        const float z = 1.f / (1.f + expf(-(iz + hz)));
        const float n = tanhf(in_ + r * hnn);
        const float hv = (1.f - z) * n + z * hold[(size_t)b * H + g];
        hn[g] = hv;
        shl[g] = selu_f(hv);
        hnew_out[(size_t)b * H + g] = cell_end ? 0.5f * (dec[(size_t)b * H + g] + hv) : hv;
    }
    if (t < 100) wc_lds[t] = W_copy[t];
    __syncthreads();
    for (int n = wvi; n < 100; n += 4){
        const float* wr = W_fuse + (size_t)n * (2*H);
        float a = 0.f;
        #pragma unroll
        for (int u = 0; u < H/64; ++u) a += shl[ln + 64*u] * wr[ln + 64*u];
        a = wred_sum(a);
        if (ln == 0) u_lds[n] = a + b_fuse[n];
    }
    if (wvi == 3){
        float a = 0.f;
        #pragma unroll
        for (int u = 0; u < H/64; ++u) a += hn[ln + 64*u] * We[ln + 64*u];
        a = wred_sum(a);
        if (ln == 0) sco[100] = a + be[0];
    }
    __syncthreads();
    const float bc = b_copy[0];
    for (int s = wvi; s < S; s += 4){
        const float* vb = v + ((size_t)b * S + s) * 100;
        float a = selu_f(u_lds[ln] + vb[ln]) * wc_lds[ln];
        if (ln + 64 < 100) a += selu_f(u_lds[ln + 64] + vb[ln + 64]) * wc_lds[ln + 64];
        a = wred_sum(a);
        if (ln == 0) sco[s] = a + bc;
    }
    __syncthreads();
    if (wvi == 0){
        const float v1 = sco[ln];
        const int i2 = ln + 64;
        const float v2 = (i2 <= S) ? sco[i2] : -INFINITY;
        const float m = wred_maxf(fmaxf(v1, v2));
        const float p1 = v1 - m, p2 = v2 - m;
        float e = expf(p1) + ((i2 <= S) ? expf(p2) : 0.f);
        const float lse = logf(wred_sum(e));
        const float q1 = p1 - lse, q2 = p2 - lse;
        float bv; int bi;
        if (q2 > q1){ bv = q2; bi = i2; } else { bv = q1; bi = ln; }
        #pragma unroll
        for (int o = 32; o > 0; o >>= 1){
            float ov = __shfl_xor(bv, o);
            int   oi = __shfl_xor(bi, o);
            if (ov > bv || (ov == bv && oi < bi)){ bv = ov; bi = oi; }
        }
        const size_t obase = (size_t)slot * B * (S+1) + (size_t)b * (S+1);
        out_copy[obase + ln] = q1;
        if (i2 <= S) out_copy[obase + i2] = q2;
        if (ln == 0){
            out_act[(size_t)aslot * B + b] = (float)bi;
            act_sh = bi;
        }
    }
    __syncthreads();
    const int act = act_sh;
    const int wd = sentence[b * S + (act < S ? act : S - 1)];
    const float* wr = word_emb + (size_t)wd * E;
    float* ebp = emb + (size_t)b * E;
    ebp[t] = wr[t];
    ebp[t + 256] = wr[t + 256];
}

extern "C" void kernel_launch(void* const* d_in, const int* in_sizes, int n_in,
                              void* d_out, int out_size, void* d_ws, size_t ws_size,
                              hipStream_t stream)
{
    (void)in_sizes; (void)n_in; (void)out_size; (void)ws_size;
    const int*   sentence = (const int*)  d_in[0];
    const float* dec      = (const float*)d_in[1];
    const float* enc      = (const float*)d_in[2];
    const float* word_emb = (const float*)d_in[3];
    const float* rel_emb  = (const float*)d_in[4];
    const float* sos      = (const float*)d_in[5];
    const float* W_comb   = (const float*)d_in[6];
    const float* b_comb   = (const float*)d_in[7];
    const float* W_attn   = (const float*)d_in[8];
    // d_in[9] = b_attn (cancels in softmax)
    const float* W_ih     = (const float*)d_in[10];
    const float* W_hh     = (const float*)d_in[11];
    const float* b_ih     = (const float*)d_in[12];
    const float* b_hh     = (const float*)d_in[13];
    const float* W_eos    = (const float*)d_in[14];
    const float* b_eos    = (const float*)d_in[15];
    const float* W_pred   = (const float*)d_in[16];
    const float* b_pred   = (const float*)d_in[17];
    const float* W_fuse   = (const float*)d_in[18];
    const float* b_fuse   = (const float*)d_in[19];
    const float* W_copy   = (const float*)d_in[20];
    const float* b_copy   = (const float*)d_in[21];

    float* out       = (float*)d_out;
    float* out_rel   = out;
    float* out_copy  = out + (size_t)NC * B * (R + 1);
    float* out_act   = out_copy + (size_t)2 * NC * B * (S + 1);

    float* p = (float*)d_ws;
    float* v_buf = p; p += (size_t)B * S * 100;       // 2.56M
    float* Wihc  = p; p += (size_t)NC * H3 * E;       // 3.93M
    float* gixc  = p; p += (size_t)NC * B * H3;       // 1.97M
    float* Wc1T  = p; p += (size_t)E * E;             // 0.26M
    float* ctx   = p; p += B * H;
    float* xc    = p; p += B * E;
    float* emb   = p; p += B * E;
    float* hb0   = p; p += B * H;
    float* hb1   = p; p += B * H;
    float* gi0   = p; p += (size_t)B * H3;
    float* gi1   = p; p += (size_t)B * H3;
    float* gh0   = p; p += (size_t)B * H3;
    float* gh1   = p; p += (size_t)B * H3;
    float* hb[2] = { hb0, hb1 };

    // ---- one-time precompute ----
    k_init<<<(B*E)/256, 256, 0, stream>>>(sos, dec, emb, hb0);
    k_ctx<<<B, 256, 0, stream>>>(enc, W_attn, ctx);
    // xc = ctx @ Wc2^T + b_comb
    k_gemm<<<dim3(4, 4, 1), 256, 0, stream>>>(
        ctx, H, 0, W_comb + E, H + E, 0, b_comb, 0,
        nullptr, 0, 0, xc, E, 0, E, H, 0);
    // Wc1^T
    k_transpose<<<dim3(8, 8), 256, 0, stream>>>(W_comb, Wc1T);
    // Wihc[c] = W_ih[c] @ Wc1   (batched z=5)
    k_gemm<<<dim3(4, H3/64, NC), 256, 0, stream>>>(
        W_ih, E, (long long)H3 * E, Wc1T, E, 0, nullptr, 0,
        nullptr, 0, 0, Wihc, E, (long long)H3 * E, E, E, 0);
    // gixc[c] = xc @ W_ih[c]^T + b_ih[c]   (batched z=5)
    k_gemm<<<dim3(H3/128, 4, NC), 256, 0, stream>>>(
        xc, E, 0, W_ih, E, (long long)H3 * E, b_ih, H3,
        nullptr, 0, 0, gixc, H3, (long long)B * H3, H3, E, 0);
    // v = selu(enc) @ Wf2^T
    k_gemm<<<dim3(1, (B*S)/64, 1), 256, 0, stream>>>(
        enc, H, 0, W_fuse + H, 2*H, 0, nullptr, 0,
        nullptr, 0, 0, v_buf, 100, 0, 100, H, 1);

    int cur = 0;
    for (int c = 0; c < NC; ++c){
        for (int t3 = 0; t3 < 3; ++t3){
            k_gru2<<<dim3(24, 4, 2), 256, 0, stream>>>(
                emb, hb[cur],
                Wihc + (size_t)c * H3 * E, W_hh + (size_t)c * H3 * H,
                gixc + (size_t)c * B * H3, b_hh + (size_t)c * H3,
                gi0, gi1, gh0, gh1);
            if (t3 == 0){
                k_rel_fused<<<B, 256, 0, stream>>>(
                    gi0, gi1, gh0, gh1, hb[cur], W_pred, b_pred, W_eos, b_eos,
                    rel_emb, out_rel, c, emb, out_act, hb[cur^1]);
            } else {
                k_copy_fused<<<B, 256, 0, stream>>>(
                    gi0, gi1, gh0, gh1, hb[cur], v_buf, W_fuse, b_fuse,
                    W_copy, b_copy, W_eos, b_eos, sentence, word_emb,
                    out_copy, 2*c + (t3-1), emb, out_act, 3*c + t3,
                    hb[cur^1], dec, (t3 == 2) ? 1 : 0);
            }
            cur ^= 1;
        }
    }
}